// Round 2
// baseline (152.560 us; speedup 1.0000x reference)
//
#include <hip/hip_runtime.h>
#include <hip/hip_bf16.h>
#include <stdint.h>

#define NTEST 4096
#define NTRAIN 16384
#define DIM 128

typedef __attribute__((ext_vector_type(8))) short short8;
typedef __attribute__((ext_vector_type(16))) float float16v;

#if __has_builtin(__builtin_amdgcn_exp2f)
#define EXP2F(x) __builtin_amdgcn_exp2f(x)
#else
#define EXP2F(x) exp2f(x)
#endif

static __device__ __forceinline__ unsigned short f32_to_bf16_rne(float f) {
    union { float f; uint32_t u; } v; v.f = f;
    uint32_t u = v.u;
    uint32_t r = u + 0x7FFFu + ((u >> 16) & 1u);
    return (unsigned short)(r >> 16);
}

// ---- Kernel 1: per-column partial sums for std (coalesced) + zero out ----
__global__ void col_stats_partial(const float* __restrict__ train,
                                  float* __restrict__ psum, float* __restrict__ psumsq,
                                  float* __restrict__ out) {
    int b = blockIdx.x;       // 256 blocks x 64 rows each
    int t = threadIdx.x;      // 256
    if (b < 16) out[b * 256 + t] = 0.f;   // zero output (re-poisoned each call)
    int col = t & 127;
    int rh = t >> 7;          // 0/1
    float s = 0.f, ss = 0.f;
    int row0 = b * 64;
    for (int r = rh; r < 64; r += 2) {
        float x = train[(size_t)(row0 + r) * DIM + col];
        s += x; ss += x * x;
    }
    __shared__ float sh_s[256], sh_ss[256];
    sh_s[t] = s; sh_ss[t] = ss;
    __syncthreads();
    if (rh == 0) {
        psum[b * DIM + col]   = sh_s[col] + sh_s[col + 128];
        psumsq[b * DIM + col] = sh_ss[col] + sh_ss[col + 128];
    }
}

// ---- Kernel 2: bandwidth + Z scalars ----
__global__ void bandwidth_kernel(const float* __restrict__ psum, const float* __restrict__ psumsq,
                                 float* __restrict__ inv_bw, float* __restrict__ scalars) {
    int t = threadIdx.x;      // 256
    int c = t & 127;
    int h = t >> 7;
    float s = 0.f, ss = 0.f;
    for (int b = h * 128; b < h * 128 + 128; ++b) { s += psum[b * DIM + c]; ss += psumsq[b * DIM + c]; }
    __shared__ float S[256], SS[256], sh[128];
    S[t] = s; SS[t] = ss;
    __syncthreads();
    if (h == 0) {
        s = S[c] + S[c + 128]; ss = SS[c] + SS[c + 128];
        float n = (float)NTRAIN;
        float var = (ss - s * s / n) / (n - 1.0f);
        float sd = fmaxf(sqrtf(var), 0.01f);
        float bw = 1.06f * sd * expf(-logf(n) / (float)(4 + DIM));
        bw = fminf(bw, 0.49f);
        inv_bw[c] = 1.0f / bw;
        sh[c] = logf(bw);
    }
    __syncthreads();
    for (int off = 64; off > 0; off >>= 1) {
        if (t < off) sh[t] += sh[t + off];
        __syncthreads();
    }
    if (t == 0) {
        float Z = 0.5f * (float)DIM * logf(2.0f * 3.14159265358979323846f) + sh[0] + logf((float)NTRAIN);
        scalars[0] = -0.5f / Z;   // term = exp(scale*sq - 1); scale < 0 (Z > 0)
    }
}

// ---- Kernel 3: fused expand: scale rows by inv_bw, bf16 RNE, exact fp32 norms ----
// blocks 0..8191: train rows -> Be/rnorm; blocks 8192..10239: test rows -> Ae/tnorm
__global__ void expand_rows(const float* __restrict__ train, const float* __restrict__ test,
                            const float* __restrict__ inv_bw,
                            unsigned short* __restrict__ Be, float* __restrict__ rnorm,
                            unsigned short* __restrict__ Ae, float* __restrict__ tnorm) {
    int t = threadIdx.x;
    int r = blockIdx.x * 2 + (t >> 7);    // global row index across [train | test]
    int k = t & 127;
    const float* src; unsigned short* dstM; float* dstN; int rr;
    if (r < NTRAIN) { src = train; dstM = Be; dstN = rnorm; rr = r; }
    else            { src = test;  dstM = Ae; dstN = tnorm; rr = r - NTRAIN; }
    float x = src[(size_t)rr * DIM + k] * inv_bw[k];
    dstM[(size_t)rr * DIM + k] = f32_to_bf16_rne(x);
    float nv = x * x;   // exact fp32 norm
    #pragma unroll
    for (int off = 32; off > 0; off >>= 1) nv += __shfl_xor(nv, off, 64);
    __shared__ float sh[4];
    if ((t & 63) == 0) sh[t >> 6] = nv;
    __syncthreads();
    if (k == 0) dstN[rr] = sh[(t >> 6)] + sh[(t >> 6) + 1];
}

// ---- Kernel 4: barrier-free, LDS-free 128x128-tile GEMM + fused exp epilogue ----
// A (test, bf16) and B (train, bf16) fragments gathered directly from global;
// Ae/Be are L2/L3-resident (5 MB total) so staging them in LDS was pure overhead.
__global__ __launch_bounds__(256, 2) void kde_main(
    const unsigned short* __restrict__ Ae, const unsigned short* __restrict__ Be,
    const float* __restrict__ tnorm, const float* __restrict__ rnorm,
    const float* __restrict__ scalars, float* __restrict__ out) {

    const int t = threadIdx.x;
    const int m0 = blockIdx.x * 128;     // 32 m-blocks
    const int grp = blockIdx.y;          // 16 n-groups x 8 tiles of 128
    const int wave = t >> 6;
    const int lane = t & 63;
    const int wm = wave >> 1, wn = wave & 1;
    const int col = lane & 31;           // operand row (m or n), and C/D col
    const int half = lane >> 5;          // k-half of operand; C/D row-group

    // term = exp(scale*sq - 1) = exp2(arg), arg = scale2*tn + (scale2*rn - log2e) + ns2a*dot
    // sq>=0 clamp with scale2<0  =>  arg = min(arg, -log2e)
    const float scale = scalars[0];
    const float scale2 = scale * 1.4426950408889634f;
    const float ns2a = -2.0f * scale2;
    const float NEGL2E = -1.4426950408889634f;

    // ---- A fragments: 64 rows x K=128 per wave, 16B/lane gathers (L1/L2-hit) ----
    short8 af[2][8];                      // 32 VGPRs
    #pragma unroll
    for (int tm = 0; tm < 2; ++tm) {
        const unsigned short* ap = Ae + (size_t)(m0 + wm * 64 + tm * 32 + col) * DIM + half * 8;
        #pragma unroll
        for (int kta = 0; kta < 8; ++kta)
            af[tm][kta] = *(const short8*)(ap + kta * 16);
    }

    // ---- pre-scaled test norms in C/D layout ----
    float tnv[2][16];
    #pragma unroll
    for (int tm = 0; tm < 2; ++tm) {
        const float* tp = tnorm + m0 + wm * 64 + tm * 32 + 4 * half;
        #pragma unroll
        for (int q = 0; q < 4; ++q) {
            float4 v = *(const float4*)(tp + q * 8);
            tnv[tm][q * 4 + 0] = scale2 * v.x;
            tnv[tm][q * 4 + 1] = scale2 * v.y;
            tnv[tm][q * 4 + 2] = scale2 * v.z;
            tnv[tm][q * 4 + 3] = scale2 * v.w;
        }
    }

    float rs[2][16];
    #pragma unroll
    for (int tm = 0; tm < 2; ++tm)
        #pragma unroll
        for (int g = 0; g < 16; ++g) rs[tm][g] = 0.f;

    // ---- 8 n-tiles of 128 train rows; no barriers anywhere ----
    for (int j = 0; j < 8; ++j) {
        const int n0 = (grp * 8 + j) * 128;

        float rnv[2];
        #pragma unroll
        for (int tn = 0; tn < 2; ++tn)
            rnv[tn] = fmaf(scale2, rnorm[n0 + wn * 64 + tn * 32 + col], NEGL2E);

        float16v acc[2][2];
        #pragma unroll
        for (int i = 0; i < 2; ++i)
            #pragma unroll
            for (int jj = 0; jj < 2; ++jj) acc[i][jj] = (float16v)(0.f);

        const unsigned short* bp = Be + (size_t)(n0 + wn * 64 + col) * DIM + half * 8;
        #pragma unroll
        for (int kta = 0; kta < 8; ++kta) {
            short8 bf0 = *(const short8*)(bp + kta * 16);           // tn=0 rows
            short8 bf1 = *(const short8*)(bp + 32 * DIM + kta * 16); // tn=1 rows (+32 rows)
            acc[0][0] = __builtin_amdgcn_mfma_f32_32x32x16_bf16(af[0][kta], bf0, acc[0][0], 0, 0, 0);
            acc[1][0] = __builtin_amdgcn_mfma_f32_32x32x16_bf16(af[1][kta], bf0, acc[1][0], 0, 0, 0);
            acc[0][1] = __builtin_amdgcn_mfma_f32_32x32x16_bf16(af[0][kta], bf1, acc[0][1], 0, 0, 0);
            acc[1][1] = __builtin_amdgcn_mfma_f32_32x32x16_bf16(af[1][kta], bf1, acc[1][1], 0, 0, 0);
        }

        // exp epilogue into register rowsums (overlaps next tile's loads/MFMA across waves)
        #pragma unroll
        for (int tm = 0; tm < 2; ++tm)
            #pragma unroll
            for (int g = 0; g < 16; ++g) {
                float c0 = tnv[tm][g];
                float sum = 0.f;
                #pragma unroll
                for (int tn = 0; tn < 2; ++tn) {
                    float arg = fminf(fmaf(ns2a, acc[tm][tn][g], c0 + rnv[tn]), NEGL2E);
                    sum += EXP2F(arg);
                }
                rs[tm][g] += sum;
            }
    }

    // ---- final: reduce across 32 cols + atomics ----
    #pragma unroll
    for (int tm = 0; tm < 2; ++tm) {
        #pragma unroll
        for (int g = 0; g < 16; ++g) {
            float v = rs[tm][g];
            #pragma unroll
            for (int off = 1; off < 32; off <<= 1)
                v += __shfl_xor(v, off, 64);   // offs 1..16 stay within 32-lane half
            if (col == 0) {
                int rowi = (g & 3) + 8 * (g >> 2) + 4 * half;
                atomicAdd(&out[m0 + wm * 64 + tm * 32 + rowi], v);
            }
        }
    }
}

extern "C" void kernel_launch(void* const* d_in, const int* in_sizes, int n_in,
                              void* d_out, int out_size, void* d_ws, size_t ws_size,
                              hipStream_t stream) {
    const float* test  = (const float*)d_in[0];
    const float* train = (const float*)d_in[1];
    float* out = (float*)d_out;

    char* ws = (char*)d_ws;
    unsigned short* Be = (unsigned short*)ws;              // 16384*128*2 = 4,194,304 B
    unsigned short* Ae = (unsigned short*)(ws + 4194304);  //  4096*128*2 = 1,048,576 B
    float* fws    = (float*)(ws + 4194304 + 1048576);
    float* rnorm  = fws;                 // 16384
    float* tnorm  = rnorm + NTRAIN;      // 4096
    float* psum   = tnorm + NTEST;       // 256*128 = 32768
    float* psumsq = psum + 32768;        // 32768
    float* inv_bw = psumsq + 32768;      // 128
    float* scalars = inv_bw + 128;       // 8

    hipLaunchKernelGGL(col_stats_partial, dim3(256), dim3(256), 0, stream, train, psum, psumsq, out);
    hipLaunchKernelGGL(bandwidth_kernel, dim3(1), dim3(256), 0, stream, psum, psumsq, inv_bw, scalars);
    hipLaunchKernelGGL(expand_rows, dim3((NTRAIN + NTEST) / 2), dim3(256), 0, stream,
                       train, test, inv_bw, Be, rnorm, Ae, tnorm);
    hipLaunchKernelGGL(kde_main, dim3(NTEST / 128, 16), dim3(256), 0, stream,
                       Ae, Be, tnorm, rnorm, scalars, out);
}